// Round 2
// baseline (485.328 us; speedup 1.0000x reference)
//
#include <hip/hip_runtime.h>
#include <hip/hip_bf16.h>
#include <math.h>

typedef float f32x4 __attribute__((ext_vector_type(4)));
typedef short bf16x8 __attribute__((ext_vector_type(8)));

#define H_DIM 4096
#define E_EXP 64
#define NTOK  16384
#define NCH   128          // K chunks of 32
#define WSTR  40           // shorts per expert row in LDS plane (32 + 8 pad = 80B)
#define PS    132          // floats per block partial: 64 psum + 64 cnt + 1 z
#define NBLK  256

__device__ __forceinline__ unsigned rne16(float v){
    unsigned u = __float_as_uint(v);
    return (u + 0x7fffu + ((u >> 16) & 1u)) >> 16;     // RNE f32->bf16 bits
}
__device__ __forceinline__ float fromb16(unsigned s){ return __uint_as_float(s << 16); }

// split 8 fp32 into 3 bf16 planes: v = h + m + l (each bf16), residual ~2^-27|v|
__device__ __forceinline__ void split8(f32x4 a, f32x4 b, bf16x8 &h, bf16x8 &m, bf16x8 &l){
#pragma unroll
    for (int j = 0; j < 8; j++){
        float v = (j < 4) ? a[j] : b[j - 4];
        unsigned hu = rne16(v);  float r1 = v  - fromb16(hu);
        unsigned mu = rne16(r1); float r2 = r1 - fromb16(mu);
        unsigned lu = rne16(r2);
        h[j] = (short)hu; m[j] = (short)mu; l[j] = (short)lu;
    }
}

#define MFMA __builtin_amdgcn_mfma_f32_16x16x32_bf16

// ---------------------------------------------------------------------------
// Main: split-bf16 MFMA gate GEMM + fused softmax/top-2/partials
// 256 blocks x 256 threads; wave w owns tokens [16w,16w+16), all 64 experts.
// ---------------------------------------------------------------------------
__global__ __launch_bounds__(256) void moe_gate_main(
    const float* __restrict__ x, const float* __restrict__ gw,
    const float* __restrict__ bias, float* __restrict__ out,
    float* __restrict__ part)
{
    __shared__ short wbuf[2][3][E_EXP * WSTR];   // double-buffered w planes (h,m,l)
    __shared__ float ls[64 * 68];                // logits [token][expert], padded
    __shared__ float bs[64], rs[64];
    __shared__ int   ia[64], ib[64];

    const int tid = threadIdx.x, bid = blockIdx.x;
    const int tok0 = bid * 64;
    const int wv = tid >> 6, l = tid & 63, l16 = l & 15, lk = l >> 4;

    if (tid < 64) bs[tid] = bias[tid];

    // A-fragment source: lane l -> x[tok0+16wv+(l&15)][c*32 + (l>>4)*8 .. +8]
    const float* xp = x + (size_t)(tok0 + 16 * wv + l16) * H_DIM + lk * 8;
    // w staging: thread -> expert tid>>2, k-quad (tid&3)*8
    const int we = tid >> 2, wk = (tid & 3) * 8;
    const float* wp = gw + (size_t)we * H_DIM + wk;
    const int wo_base = we * WSTR + wk;

    f32x4 acc[4] = {};   // C-frags for expert groups 0..3 (static-indexed)

    // ---- prologue: stage w chunk0 -> buf0; prefetch x chunks 0,1; w chunk1 ----
    f32x4 w0a = *(const f32x4*)(wp);
    f32x4 w0b = *(const f32x4*)(wp + 4);
    f32x4 xe0 = *(const f32x4*)(xp);
    f32x4 xe1 = *(const f32x4*)(xp + 4);
    f32x4 xo0 = *(const f32x4*)(xp + 32);
    f32x4 xo1 = *(const f32x4*)(xp + 36);
    f32x4 wn0 = *(const f32x4*)(wp + 32);
    f32x4 wn1 = *(const f32x4*)(wp + 36);
    {
        bf16x8 h, m, lo; split8(w0a, w0b, h, m, lo);
        *(bf16x8*)&wbuf[0][0][wo_base] = h;
        *(bf16x8*)&wbuf[0][1][wo_base] = m;
        *(bf16x8*)&wbuf[0][2][wo_base] = lo;
    }
    __syncthreads();

    for (int cp = 0; cp < 64; cp++){
        const int c0 = 2 * cp;
        // ======== even phase: chunk c0 (read buf0, write buf1 = w(c0+1)) ========
        {
            bf16x8 xh, xm, xl; split8(xe0, xe1, xh, xm, xl);
            if (cp < 63){
                xe0 = *(const f32x4*)(xp + (c0 + 2) * 32);
                xe1 = *(const f32x4*)(xp + (c0 + 2) * 32 + 4);
            }
            {
                bf16x8 h, m, lo; split8(wn0, wn1, h, m, lo);
                *(bf16x8*)&wbuf[1][0][wo_base] = h;
                *(bf16x8*)&wbuf[1][1][wo_base] = m;
                *(bf16x8*)&wbuf[1][2][wo_base] = lo;
            }
            if (cp < 63){
                wn0 = *(const f32x4*)(wp + (c0 + 2) * 32);
                wn1 = *(const f32x4*)(wp + (c0 + 2) * 32 + 4);
            }
#pragma unroll
            for (int g = 0; g < 4; g++){
                const int wo = (g * 16 + l16) * WSTR + lk * 8;
                bf16x8 wh = *(const bf16x8*)&wbuf[0][0][wo];
                bf16x8 wm = *(const bf16x8*)&wbuf[0][1][wo];
                bf16x8 wl = *(const bf16x8*)&wbuf[0][2][wo];
                acc[g] = MFMA(xh, wh, acc[g], 0, 0, 0);
                acc[g] = MFMA(xm, wh, acc[g], 0, 0, 0);
                acc[g] = MFMA(xh, wm, acc[g], 0, 0, 0);
                acc[g] = MFMA(xm, wm, acc[g], 0, 0, 0);
                acc[g] = MFMA(xh, wl, acc[g], 0, 0, 0);
                acc[g] = MFMA(xl, wh, acc[g], 0, 0, 0);
            }
        }
        __syncthreads();
        // ======== odd phase: chunk c0+1 (read buf1, write buf0 = w(c0+2)) ========
        {
            bf16x8 xh, xm, xl; split8(xo0, xo1, xh, xm, xl);
            if (cp < 63){
                xo0 = *(const f32x4*)(xp + (c0 + 3) * 32);
                xo1 = *(const f32x4*)(xp + (c0 + 3) * 32 + 4);
            }
            if (cp < 63){
                bf16x8 h, m, lo; split8(wn0, wn1, h, m, lo);   // wn = w(c0+2)
                *(bf16x8*)&wbuf[0][0][wo_base] = h;
                *(bf16x8*)&wbuf[0][1][wo_base] = m;
                *(bf16x8*)&wbuf[0][2][wo_base] = lo;
                wn0 = *(const f32x4*)(wp + (c0 + 3) * 32);
                wn1 = *(const f32x4*)(wp + (c0 + 3) * 32 + 4);
            }
#pragma unroll
            for (int g = 0; g < 4; g++){
                const int wo = (g * 16 + l16) * WSTR + lk * 8;
                bf16x8 wh = *(const bf16x8*)&wbuf[1][0][wo];
                bf16x8 wm = *(const bf16x8*)&wbuf[1][1][wo];
                bf16x8 wl = *(const bf16x8*)&wbuf[1][2][wo];
                acc[g] = MFMA(xh, wh, acc[g], 0, 0, 0);
                acc[g] = MFMA(xm, wh, acc[g], 0, 0, 0);
                acc[g] = MFMA(xh, wm, acc[g], 0, 0, 0);
                acc[g] = MFMA(xm, wm, acc[g], 0, 0, 0);
                acc[g] = MFMA(xh, wl, acc[g], 0, 0, 0);
                acc[g] = MFMA(xl, wh, acc[g], 0, 0, 0);
            }
        }
        __syncthreads();
    }

    // ---- C-frag -> logits LDS: token=(16wv + lk*4 + r), expert=(16g + l16) ----
#pragma unroll
    for (int g = 0; g < 4; g++)
#pragma unroll
        for (int r = 0; r < 4; r++)
            ls[(16 * wv + lk * 4 + r) * 68 + g * 16 + l16] = acc[g][r];
    __syncthreads();

    // ---- per-token epilogue: wave 0, one token per lane ----
    float zsq = 0.f;
    if (tid < 64) {
        const float invTemp = (1.0f / 3.0f);
        float m = -1e30f, m2 = -1e30f;
        int i1 = 0, i2 = 0;
        for (int e = 0; e < E_EXP; e++) {
            float v = (ls[tid * 68 + e] + bs[e]) * invTemp;
            ls[tid * 68 + e] = v;
            if (v > m)       { m2 = m; i2 = i1; m = v; i1 = e; }
            else if (v > m2) { m2 = v; i2 = e; }
        }
        float s = 0.f;
        for (int e = 0; e < E_EXP; e++) {
            float p = expf(ls[tid * 68 + e] - m);
            ls[tid * 68 + e] = p;
            s += p;
        }
        rs[tid] = 1.0f / s;
        ia[tid] = i1; ib[tid] = i2;

        float p2    = expf(m2 - m);
        float inv12 = 1.0f / (1.0f + p2);
        out[(size_t)(tok0 + tid) * 2 + 0] = inv12;
        out[(size_t)(tok0 + tid) * 2 + 1] = p2 * inv12;
        out[(size_t)NTOK * 2 + (size_t)(tok0 + tid) * 2 + 0] = (float)i1;
        out[(size_t)NTOK * 2 + (size_t)(tok0 + tid) * 2 + 1] = (float)i2;

        float lse = m + logf(s);
        zsq = lse * lse;
#pragma unroll
        for (int o = 32; o; o >>= 1) zsq += __shfl_xor(zsq, o);
    }
    __syncthreads();

    // ---- per-expert block partials ----
    if (tid < E_EXP) {
        float psum = 0.f, csum = 0.f;
        for (int t = 0; t < 64; t++) {
            psum += ls[t * 68 + tid] * rs[t];
            csum += (ia[t] == tid ? 1.f : 0.f) + (ib[t] == tid ? 1.f : 0.f);
        }
        part[bid * PS + tid]      = psum;
        part[bid * PS + 64 + tid] = csum;
        if (tid == 0) part[bid * PS + 128] = zsq;
    }
}

// ---------------------------------------------------------------------------
// Loss reduction: 1 block x 1024 threads, coalesced tree reduce
// ---------------------------------------------------------------------------
__global__ __launch_bounds__(1024) void moe_gate_loss(
    const float* __restrict__ part, float* __restrict__ out)
{
    __shared__ float spS[16][64], scS[16][64], zS[256];
    const int tid = threadIdx.x;
    const int e = tid & 63, g = tid >> 6;       // 16 block-groups x 64 experts
    float sp = 0.f, sc = 0.f;
    for (int b = g; b < NBLK; b += 16) {
        sp += part[b * PS + e];
        sc += part[b * PS + 64 + e];
    }
    spS[g][e] = sp; scS[g][e] = sc;
    if (tid < 256) zS[tid] = part[tid * PS + 128];
    __syncthreads();

    if (tid < 64) {
        float tsp = 0.f, tsc = 0.f;
#pragma unroll
        for (int g2 = 0; g2 < 16; g2++) { tsp += spS[g2][tid]; tsc += scS[g2][tid]; }
        float zp = zS[tid] + zS[tid + 64] + zS[tid + 128] + zS[tid + 192];
        const float invN = 1.0f / (float)NTOK;
        float dot = (tsc * invN) * (tsp * invN);
#pragma unroll
        for (int o = 32; o; o >>= 1) {
            dot += __shfl_xor(dot, o);
            zp  += __shfl_xor(zp, o);
        }
        if (tid == 0)
            out[(size_t)NTOK * 4] = 0.01f * 64.0f * dot + 1e-4f * zp * invN;
    }
}

// ---------------------------------------------------------------------------
extern "C" void kernel_launch(void* const* d_in, const int* in_sizes, int n_in,
                              void* d_out, int out_size, void* d_ws, size_t ws_size,
                              hipStream_t stream)
{
    const float* x    = (const float*)d_in[0];
    const float* gw   = (const float*)d_in[1];
    const float* bias = (const float*)d_in[2];
    float* out  = (float*)d_out;
    float* part = (float*)d_ws;   // NBLK * PS floats = 132 KiB

    moe_gate_main<<<NBLK, 256, 0, stream>>>(x, gw, bias, out, part);
    moe_gate_loss<<<1, 1024, 0, stream>>>(part, out);
}